// Round 11
// baseline (217.661 us; speedup 1.0000x reference)
//
#include <hip/hip_runtime.h>
#include <hip/hip_bf16.h>
#include <cstdint>
#include <cstddef>

#define HID 512
#define T_SZ 4096

typedef __bf16 bf16x8 __attribute__((ext_vector_type(8)));
typedef float f32x4 __attribute__((ext_vector_type(4)));

__device__ __forceinline__ unsigned short f2bf_rne(float f) {
    unsigned int u = __float_as_uint(f);
    unsigned int r = (u + 0x7FFFu + ((u >> 16) & 1u)) >> 16;
    return (unsigned short)r;
}

__device__ __forceinline__ bf16x8 pack8(float4 x0, float4 x1) {
    bf16x8 r;
    r[0] = (__bf16)x0.x; r[1] = (__bf16)x0.y; r[2] = (__bf16)x0.z; r[3] = (__bf16)x0.w;
    r[4] = (__bf16)x1.x; r[5] = (__bf16)x1.y; r[6] = (__bf16)x1.z; r[7] = (__bf16)x1.w;
    return r;
}

__device__ __forceinline__ float fast_tanh(float x) {
    float e = __expf(2.0f * x);
    return 1.0f - 2.0f / (e + 1.0f);
}

__device__ __forceinline__ void gload_lds16(const void* g, void* l) {
    __builtin_amdgcn_global_load_lds(
        (const __attribute__((address_space(1))) unsigned int*)g,
        (__attribute__((address_space(3))) unsigned int*)l, 16, 0, 0);
}

// ---------------- kernel 1: s[b][n] = dot(dec[b,:], Ws[n,:]) ----------------
__global__ void k_s(const float* __restrict__ dec, const float* __restrict__ Ws,
                    float* __restrict__ s) {
    int idx = blockIdx.x * 256 + threadIdx.x;   // 16384 = 32*512
    int b = idx >> 9, n = idx & 511;
    const float4* dp = reinterpret_cast<const float4*>(dec + (size_t)b * HID);
    const float4* wp = reinterpret_cast<const float4*>(Ws + (size_t)n * HID);
    float acc = 0.f;
#pragma unroll 8
    for (int i = 0; i < HID / 4; ++i) {
        float4 d = dp[i], w = wp[i];
        acc += d.x * w.x + d.y * w.y + d.z * w.z + d.w * w.w;
    }
    s[idx] = acc;
}

// ------------- kernel 2: pack W_h -> bf16 fragments (kk-major) --------------
// Chunk index = kk*2048 + n4*64 + (g*16 + c); chunk (uint4) holds
// W[n4*16 + c][kk*32 + g*8 + j], j=0..7 as bf16.
__global__ void k_pack(const float* __restrict__ Wh, uint4* __restrict__ Wb) {
    int idx = blockIdx.x * 256 + threadIdx.x;   // 32768, 8 elems each
    int n = idx >> 6;
    int k0 = (idx & 63) * 8;
    const float4* p = reinterpret_cast<const float4*>(Wh + (size_t)n * HID + k0);
    float4 x0 = p[0], x1 = p[1];
    uint4 w;
    w.x = f2bf_rne(x0.x) | ((unsigned)f2bf_rne(x0.y) << 16);
    w.y = f2bf_rne(x0.z) | ((unsigned)f2bf_rne(x0.w) << 16);
    w.z = f2bf_rne(x1.x) | ((unsigned)f2bf_rne(x1.y) << 16);
    w.w = f2bf_rne(x1.z) | ((unsigned)f2bf_rne(x1.w) << 16);
    int n4 = n >> 4, c = n & 15, kk = k0 >> 5, g = (k0 >> 3) & 3;
    Wb[(size_t)kk * 2048 + n4 * 64 + g * 16 + c] = w;
}

// ------------- kernel 3: fused h = enc@Wh^T ; e_part = sum tanh(h+s).v ------
// BM=256, BN=256 (h-half), BK=64, nt=8 K-tiles. 512 threads = 8 waves (2mx4n),
// wave tile 128x64 (8x4 frags, acc=128). ONE barrier per K-tile; 512 MFMA
// (~2500 CU-cyc) per barrier. A: fp32 global->regs issued at iter start,
// cvt+ds_write AFTER compute (compiler's vmcnt wait is compute-covered).
// B: global_load_lds from L2-resident Wb, issued before A (in-order retire
// => drained by A's wait). All LDS linear-in-lane: zero bank conflicts.
__global__ void __launch_bounds__(512, 2) k_gemm_e(
    const float* __restrict__ enc, const uint4* __restrict__ Wb,
    const float* __restrict__ s, const float* __restrict__ v,
    float* __restrict__ part_e) {
    __shared__ __align__(16) unsigned char Abuf[2][32768];  // 256r x 64k bf16
    __shared__ __align__(16) unsigned char Bbuf[2][32768];  // 256n x 64k bf16
    __shared__ float red[4][256];

    const int tid = threadIdx.x;
    // bijective XCD swizzle: 1024 blocks = 8 XCD x 128; h-pairs adjacent.
    const int p = blockIdx.x;
    const int logical = (p & 7) * 128 + (p >> 3);
    const int h = logical & 1;
    const int mt = logical >> 1;            // 0..511
    const size_t row0 = (size_t)mt * 256;
    const int b = (int)(row0 >> 12);

    const int lane = tid & 63, wid = tid >> 6;
    const int c16 = lane & 15, g4 = lane >> 4;
    const int wm = wid >> 2, wn = wid & 3;  // 2m x 4n wave grid

    // epilogue constants (this wave's 64-col strip)
    float sv_s[4], sv_v[4];
#pragma unroll
    for (int ni = 0; ni < 4; ++ni) {
        int n = h * 256 + wn * 64 + ni * 16 + c16;
        sv_s[ni] = s[b * HID + n];
        sv_v[ni] = v[n];
    }

    // ---- A staging geometry: thread owns chunks {tid + i*512}, i=0..3 ----
    // chunk ch: kk2=ch>>10, rem=ch&1023, rt=rem>>6, g=(rem>>4)&3, cc=rem&15
    //   -> row = rt*16+cc, koff = kk2*32 + g*8. Wave covers 16 rows x 128B:
    //   fully-consumed cache lines.
    const float* Asrc[4];
    int Adst[4];
#pragma unroll
    for (int i = 0; i < 4; ++i) {
        int ch = tid + i * 512;
        int kk2 = ch >> 10, rem = ch & 1023;
        int rt = rem >> 6, g = (rem >> 4) & 3, cc = rem & 15;
        Asrc[i] = enc + (row0 + rt * 16 + cc) * HID + kk2 * 32 + g * 8;
        Adst[i] = ch * 16;
    }

    float4 ar[8];   // A staging regs (32 VGPR), single slot (lead-1)

    // ================= prologue: stage tile 0 =================
#pragma unroll
    for (int r = 0; r < 4; ++r) {
        int j = wid * 4 + r, kk2 = j >> 4, n4o = j & 15;
        gload_lds16(Wb + (size_t)kk2 * 2048 + (h * 16 + n4o) * 64 + lane,
                    &Bbuf[0][(kk2 * 1024 + n4o * 64) * 16]);
    }
#pragma unroll
    for (int i = 0; i < 4; ++i) {
        ar[2 * i]     = *reinterpret_cast<const float4*>(Asrc[i]);
        ar[2 * i + 1] = *reinterpret_cast<const float4*>(Asrc[i] + 4);
    }
#pragma unroll
    for (int i = 0; i < 4; ++i)   // compiler waits A-loads; B older => drained
        *reinterpret_cast<bf16x8*>(&Abuf[0][Adst[i]]) = pack8(ar[2 * i], ar[2 * i + 1]);
    asm volatile("s_waitcnt lgkmcnt(0)\n\ts_barrier" ::: "memory");

    f32x4 acc[8][4] = {};   // [mi][ni]

#pragma unroll
    for (int t = 0; t < 8; ++t) {
        const int cur = t & 1, nxt = cur ^ 1;
        // 1) issue B(t+1) gload_lds (to LDS; no regs held)
        if (t < 7) {
#pragma unroll
            for (int r = 0; r < 4; ++r) {
                int j = wid * 4 + r, kk2 = j >> 4, n4o = j & 15;
                gload_lds16(Wb + (size_t)(2 * (t + 1) + kk2) * 2048
                                + (h * 16 + n4o) * 64 + lane,
                            &Bbuf[nxt][(kk2 * 1024 + n4o * 64) * 16]);
            }
            // 2) issue A(t+1) global loads -> regs (newest vmem ops)
#pragma unroll
            for (int i = 0; i < 4; ++i) {
                ar[2 * i]     = *reinterpret_cast<const float4*>(Asrc[i] + (t + 1) * 64);
                ar[2 * i + 1] = *reinterpret_cast<const float4*>(Asrc[i] + (t + 1) * 64 + 4);
            }
        }
        // 3) compute tile t: 2 kk-halves x (2 mi-halves x 16 MFMA)
#pragma unroll
        for (int kk2 = 0; kk2 < 2; ++kk2) {
            bf16x8 bfr[4];
#pragma unroll
            for (int ni = 0; ni < 4; ++ni)
                bfr[ni] = *reinterpret_cast<const bf16x8*>(
                    &Bbuf[cur][(kk2 * 1024 + (wn * 4 + ni) * 64 + lane) * 16]);
#pragma unroll
            for (int mh = 0; mh < 2; ++mh) {
                bf16x8 afr[4];
#pragma unroll
                for (int i = 0; i < 4; ++i)
                    afr[i] = *reinterpret_cast<const bf16x8*>(
                        &Abuf[cur][(kk2 * 1024 + (wm * 8 + mh * 4 + i) * 64 + lane) * 16]);
                __builtin_amdgcn_s_setprio(1);
#pragma unroll
                for (int i = 0; i < 4; ++i)
#pragma unroll
                    for (int ni = 0; ni < 4; ++ni)
                        acc[mh * 4 + i][ni] = __builtin_amdgcn_mfma_f32_16x16x32_bf16(
                            afr[i], bfr[ni], acc[mh * 4 + i][ni], 0, 0, 0);
                __builtin_amdgcn_s_setprio(0);
            }
        }
        // 4) cvt + ds_write A(t+1) AFTER compute: the vmcnt wait the compiler
        //    inserts here (for the A-loads) is covered by ~2500 cyc of MFMA.
        if (t < 7) {
            __builtin_amdgcn_sched_barrier(0);   // pin: compute before write
#pragma unroll
            for (int i = 0; i < 4; ++i)
                *reinterpret_cast<bf16x8*>(&Abuf[nxt][Adst[i]]) =
                    pack8(ar[2 * i], ar[2 * i + 1]);
            // B(t+1) was drained by the A-wait (issued earlier, in-order).
            asm volatile("s_waitcnt lgkmcnt(0)\n\ts_barrier" ::: "memory");
        }
    }

    // ---- epilogue: e_part[row] = sum_n tanh(h + s[n]) * v[n] (64-col strip)
    float e_part[8][4] = {};   // [mi][r]
#pragma unroll
    for (int ni = 0; ni < 4; ++ni) {
        float sn = sv_s[ni], vn = sv_v[ni];
#pragma unroll
        for (int mi = 0; mi < 8; ++mi)
#pragma unroll
            for (int r = 0; r < 4; ++r)
                e_part[mi][r] += fast_tanh(acc[mi][ni][r] + sn) * vn;
    }
    // reduce across the 16 n-residue lanes (bits 0..3 of lane)
#pragma unroll
    for (int mm = 1; mm <= 8; mm <<= 1)
#pragma unroll
        for (int mi = 0; mi < 8; ++mi)
#pragma unroll
            for (int r = 0; r < 4; ++r)
                e_part[mi][r] += __shfl_xor(e_part[mi][r], mm);

    if (c16 == 0) {
#pragma unroll
        for (int mi = 0; mi < 8; ++mi)
#pragma unroll
            for (int r = 0; r < 4; ++r)
                red[wn][wm * 128 + mi * 16 + g4 * 4 + r] = e_part[mi][r];
    }
    __syncthreads();
    if (tid < 256)
        part_e[(size_t)h * 131072 + row0 + tid] =
            red[0][tid] + red[1][tid] + red[2][tid] + red[3][tid];
}

// ---------------- kernel 4: e = part0+part1; masked softmax -> a ------------
__global__ void k_softmax(const float* __restrict__ part_e, float* __restrict__ a,
                          const int* __restrict__ mask) {
    int b = blockIdx.x, tid = threadIdx.x;     // 1024 threads
    int lane = tid & 63, wid = tid >> 6;       // 16 waves
    __shared__ float red[16];
    float vals[4]; int ms[4];
    float mx = -1e30f;
#pragma unroll
    for (int j = 0; j < 4; ++j) {
        size_t t = (size_t)b * T_SZ + tid + j * 1024;
        vals[j] = part_e[t] + part_e[131072 + t];
        ms[j] = mask[t];
        if (ms[j]) mx = fmaxf(mx, vals[j]);
    }
#pragma unroll
    for (int m = 32; m >= 1; m >>= 1) mx = fmaxf(mx, __shfl_xor(mx, m));
    if (lane == 0) red[wid] = mx;
    __syncthreads();
    if (tid == 0) {
        float m2 = red[0];
        for (int i = 1; i < 16; ++i) m2 = fmaxf(m2, red[i]);
        red[0] = m2;
    }
    __syncthreads();
    mx = red[0];
    __syncthreads();
    float pv[4]; float sum = 0.f;
#pragma unroll
    for (int j = 0; j < 4; ++j) { pv[j] = ms[j] ? __expf(vals[j] - mx) : 0.f; sum += pv[j]; }
#pragma unroll
    for (int m = 32; m >= 1; m >>= 1) sum += __shfl_xor(sum, m);
    if (lane == 0) red[wid] = sum;
    __syncthreads();
    if (tid == 0) {
        float s2 = 0.f;
        for (int i = 0; i < 16; ++i) s2 += red[i];
        red[0] = s2;
    }
    __syncthreads();
    float inv = 1.f / red[0];
#pragma unroll
    for (int j = 0; j < 4; ++j)
        a[(size_t)b * T_SZ + tid + j * 1024] = pv[j] * inv;
}

// ---------------- kernel 5: ctx partials over T-chunks ----------------------
__global__ void k_ctx(const float* __restrict__ enc, const float* __restrict__ a,
                      float2* __restrict__ part) {
    int ts = blockIdx.x, b = blockIdx.y, tid = threadIdx.x;   // 32 x 32, 256 thr
    size_t rbase = (size_t)b * T_SZ + (size_t)ts * 128;
    const float2* ep = reinterpret_cast<const float2*>(enc + rbase * HID) + tid;
    const float* ap = a + rbase;
    float ax = 0.f, ay = 0.f, bx = 0.f, by = 0.f;
#pragma unroll 2
    for (int t = 0; t < 128; t += 2) {
        float a0 = ap[t], a1 = ap[t + 1];
        float2 e0 = ep[(size_t)t * 256], e1 = ep[(size_t)(t + 1) * 256];
        ax += a0 * e0.x; ay += a0 * e0.y;
        bx += a1 * e1.x; by += a1 * e1.y;
    }
    float2 r; r.x = ax + bx; r.y = ay + by;
    part[(size_t)(b * 32 + ts) * 256 + tid] = r;
}

// ---------------- kernel 6: reduce partials -> ctx --------------------------
__global__ void k_ctxred(const float* __restrict__ part, float* __restrict__ ctx) {
    int idx = blockIdx.x * 256 + threadIdx.x;   // 16384
    int b = idx >> 9, h = idx & 511;
    float sum = 0.f;
#pragma unroll
    for (int ts = 0; ts < 32; ++ts) sum += part[(size_t)(b * 32 + ts) * 512 + h];
    ctx[idx] = sum;
}

extern "C" void kernel_launch(void* const* d_in, const int* in_sizes, int n_in,
                              void* d_out, int out_size, void* d_ws, size_t ws_size,
                              hipStream_t stream) {
    const float* enc  = (const float*)d_in[0];   // [32,4096,512]
    const int*   mask = (const int*)d_in[1];     // [32,4096]
    const float* dec  = (const float*)d_in[2];   // [32,512]
    const float* Wh   = (const float*)d_in[3];   // [512,512]
    const float* Ws   = (const float*)d_in[4];   // [512,512]
    const float* v    = (const float*)d_in[5];   // [512]

    float* out = (float*)d_out;
    float* ctx = out;                // 16384 floats
    float* a   = out + 16384;        // 131072 floats

    // ws layout (floats): s[16384] | Wb (131072 f-slots) | part_e[262144] | part[524288]
    float* ws     = (float*)d_ws;
    float* s      = ws;
    uint4* Wb     = (uint4*)(ws + 16384);
    float* part_e = ws + 16384 + 131072;
    float* part   = part_e + 262144;

    hipLaunchKernelGGL(k_s,      dim3(64),      dim3(256),  0, stream, dec, Ws, s);
    hipLaunchKernelGGL(k_pack,   dim3(128),     dim3(256),  0, stream, Wh, Wb);
    hipLaunchKernelGGL(k_gemm_e, dim3(1024),    dim3(512),  0, stream, enc, Wb, s, v, part_e);
    hipLaunchKernelGGL(k_softmax,dim3(32),      dim3(1024), 0, stream, part_e, a, mask);
    hipLaunchKernelGGL(k_ctx,    dim3(32, 32),  dim3(256),  0, stream, enc, a, (float2*)part);
    hipLaunchKernelGGL(k_ctxred, dim3(64),      dim3(256),  0, stream, part, ctx);
}